// Round 17
// baseline (116.844 us; speedup 1.0000x reference)
//
#include <hip/hip_runtime.h>
#include <math.h>

constexpr int kNumSeqs      = 64;
constexpr int kNumHeads     = 32;
constexpr int kNumKVHeads   = 8;
constexpr int kHeadDim      = 128;
constexpr int kGQA          = 4;       // 32/8
constexpr int kKVBlock      = 16;
constexpr int kMaxSeqlen    = 1024;
constexpr int kBlocksPerSeq = 64;
constexpr int kChunk        = 32;      // positions per work item
constexpr int kMaxChunks    = kMaxSeqlen / kChunk;          // 32
constexpr int kNumSH        = kNumSeqs * kNumKVHeads;       // 512
constexpr float kScale      = 0.08838834764831845f;  // 1/sqrt(128)
constexpr float kEps        = 1e-6f;

// ws layout (floats):
//   acc : [sh][chunk][g][128] -> 512*32*4*128 = 8,388,608
//   m   : [sh][chunk][g]      -> 65,536
//   l   : [sh][chunk][g]      -> 65,536
constexpr size_t kAccElems = (size_t)kNumSH * kMaxChunks * kGQA * kHeadDim;
constexpr size_t kMOff     = kAccElems;
constexpr size_t kLOff     = kAccElems + (size_t)kNumSH * kMaxChunks * kGQA;

// Single-buffered round-6 micro-structure (~56 VGPR, fits the (256,4) 64-VGPR cap, no spills).
// Block = (seq, 32-pos chunk) x ALL 8 kv-heads: the 4 waves read each 4KB KV row end-to-end
// -> 16KB K + 16KB V contiguous per batch (DRAM-granularity test vs 512B@4KB-stride).
__launch_bounds__(256, 4)
__global__ void paged_attn_part(
    const float* __restrict__ q,
    const float* __restrict__ k,
    const float* __restrict__ v,
    const float* __restrict__ k_cache,
    const float* __restrict__ v_cache,
    const float* __restrict__ qw,
    const float* __restrict__ kw,
    const float* __restrict__ cos_cache,
    const float* __restrict__ sin_cache,
    const int*   __restrict__ position,
    const int*   __restrict__ block_tables,
    const int*   __restrict__ context_lens,
    float* __restrict__ ws)
{
  // chunk-major item order: always-live chunks 0..15 (ctx>=512) dispatch first.
  const int item = blockIdx.x;
  const int c    = item >> 6;            // chunk 0..31
  const int s    = item & 63;

  const int ctx = context_lens[s];
  const int n0  = c * kChunk;
  if (n0 >= ctx) return;                 // dead item: exit immediately

  const int tid  = threadIdx.x;
  const int wave = tid >> 6;
  const int lane = tid & 63;
  const int half = lane >> 5;            // which head of the wave's pair
  const int j    = lane & 31;            // dim group: floats [4j, 4j+4)
  const int hh   = wave * 2 + half;      // kv-head owned by this half-wave

  const int pos      = position[s];      // == ctx-1
  const int cnt      = min(n0 + kChunk, ctx) - n0;   // 1..32
  const int posLocal = pos - n0;
  const bool haspos  = (posLocal >= 0) && (posLocal < cnt);

  __shared__ __align__(16) float q_lds[kNumHeads][kHeadDim];     // 16 KB
  __shared__ __align__(16) float kn_lds[kNumKVHeads][kHeadDim];  //  4 KB
  __shared__ __align__(16) float vn_lds[kNumKVHeads][kHeadDim];  //  4 KB
  __shared__ int bt_lds[kChunk / kKVBlock];                      //  2 entries

  // ---------------- prologue (verified in r10): RMSNorm + RoPE for this half-wave's heads --
  const float c0 = cos_cache[pos * 64 + j];
  const float c1 = cos_cache[pos * 64 + 32 + j];
  const float s0 = sin_cache[pos * 64 + j];
  const float s1 = sin_cache[pos * 64 + 32 + j];

  {
    const float w0 = qw[j], w1 = qw[j + 32], w2 = qw[j + 64], w3 = qw[j + 96];
    #pragma unroll
    for (int g = 0; g < kGQA; ++g) {
      const int qh = hh * kGQA + g;
      const float* qrow = q + (size_t)s * (kNumHeads * kHeadDim) + qh * kHeadDim;
      float x0 = qrow[j], x1 = qrow[j + 32], x2 = qrow[j + 64], x3 = qrow[j + 96];
      float ss = x0 * x0 + x1 * x1 + x2 * x2 + x3 * x3;
      #pragma unroll
      for (int off = 16; off >= 1; off >>= 1) ss += __shfl_xor(ss, off);
      const float r = rsqrtf(ss * (1.0f / kHeadDim) + kEps);
      x0 *= r * w0; x1 *= r * w1; x2 *= r * w2; x3 *= r * w3;
      q_lds[qh][j]      = (x0 * c0 - x2 * s0) * kScale;
      q_lds[qh][j + 32] = (x1 * c1 - x3 * s1) * kScale;
      q_lds[qh][j + 64] = (x2 * c0 + x0 * s0) * kScale;
      q_lds[qh][j + 96] = (x3 * c1 + x1 * s1) * kScale;
    }
  }
  if (haspos) {   // only the chunk containing pos needs the new k/v
    const float w0 = kw[j], w1 = kw[j + 32], w2 = kw[j + 64], w3 = kw[j + 96];
    const float* krow = k + (size_t)s * (kNumKVHeads * kHeadDim) + hh * kHeadDim;
    float x0 = krow[j], x1 = krow[j + 32], x2 = krow[j + 64], x3 = krow[j + 96];
    float ss = x0 * x0 + x1 * x1 + x2 * x2 + x3 * x3;
    #pragma unroll
    for (int off = 16; off >= 1; off >>= 1) ss += __shfl_xor(ss, off);
    const float r = rsqrtf(ss * (1.0f / kHeadDim) + kEps);
    x0 *= r * w0; x1 *= r * w1; x2 *= r * w2; x3 *= r * w3;
    kn_lds[hh][j]      = x0 * c0 - x2 * s0;
    kn_lds[hh][j + 32] = x1 * c1 - x3 * s1;
    kn_lds[hh][j + 64] = x2 * c0 + x0 * s0;
    kn_lds[hh][j + 96] = x3 * c1 + x1 * s1;
    const float* vrow = v + (size_t)s * (kNumKVHeads * kHeadDim) + hh * kHeadDim;
    *(float4*)&vn_lds[hh][4 * j] = *(const float4*)(vrow + 4 * j);
  }
  if (tid < kChunk / kKVBlock)
    bt_lds[tid] = block_tables[s * kBlocksPerSeq + c * (kChunk / kKVBlock) + tid];
  __syncthreads();   // B1 (only barrier)

  float4 qf[kGQA];
  #pragma unroll
  for (int g = 0; g < kGQA; ++g)
    qf[g] = *(const float4*)&q_lds[hh * kGQA + g][4 * j];
  const float4 knf = *(const float4*)&kn_lds[hh][4 * j];  // used only when haspos
  const float4 vnf = *(const float4*)&vn_lds[hh][4 * j];

  // ---------------- flash loop: 4 consecutive positions/batch, full-row contiguous ----------
  float mrun[kGQA], lrun[kGQA];
  float4 acc[kGQA];
  #pragma unroll
  for (int g = 0; g < kGQA; ++g) {
    mrun[g] = -3.0e38f; lrun[g] = 0.0f;
    acc[g] = make_float4(0.f, 0.f, 0.f, 0.f);
  }

  const int nb = (cnt + 3) >> 2;       // 1..8 batches
  for (int b = 0; b < nb; ++b) {
    float4 kv[4], vv[4];
    bool   val[4];
    #pragma unroll
    for (int jj = 0; jj < 4; ++jj) {
      const int p = 4 * b + jj;
      val[jj] = (p < cnt);
      const int pp = val[jj] ? p : (cnt - 1);
      const int blk = bt_lds[pp >> 4];
      const size_t off =
          ((size_t)blk * kKVBlock + (pp & 15)) * (kNumKVHeads * kHeadDim) +
          hh * kHeadDim + 4 * j;
      kv[jj] = *(const float4*)(k_cache + off);
      vv[jj] = *(const float4*)(v_cache + off);
      if (haspos && pp == posLocal) { kv[jj] = knf; vv[jj] = vnf; }  // virtual insert
    }

    float sg[4][kGQA];
    #pragma unroll
    for (int jj = 0; jj < 4; ++jj) {
      #pragma unroll
      for (int g = 0; g < kGQA; ++g)
        sg[jj][g] = qf[g].x * kv[jj].x + qf[g].y * kv[jj].y +
                    qf[g].z * kv[jj].z + qf[g].w * kv[jj].w;
    }
    #pragma unroll
    for (int off = 16; off >= 1; off >>= 1) {   // reduce within 32-lane half-wave
      #pragma unroll
      for (int jj = 0; jj < 4; ++jj) {
        #pragma unroll
        for (int g = 0; g < kGQA; ++g) sg[jj][g] += __shfl_xor(sg[jj][g], off);
      }
    }
    #pragma unroll
    for (int jj = 0; jj < 4; ++jj) {
      if (!val[jj]) {
        #pragma unroll
        for (int g = 0; g < kGQA; ++g) sg[jj][g] = -3.0e38f;
      }
    }

    // online softmax update (per half-wave)
    #pragma unroll
    for (int g = 0; g < kGQA; ++g) {
      const float mb = fmaxf(fmaxf(sg[0][g], sg[1][g]), fmaxf(sg[2][g], sg[3][g]));
      const float mn = fmaxf(mrun[g], mb);
      const float f  = __expf(mrun[g] - mn);
      const float p0 = __expf(sg[0][g] - mn);
      const float p1 = __expf(sg[1][g] - mn);
      const float p2 = __expf(sg[2][g] - mn);
      const float p3 = __expf(sg[3][g] - mn);
      lrun[g] = lrun[g] * f + (p0 + p1 + p2 + p3);
      acc[g].x = acc[g].x * f + p0 * vv[0].x + p1 * vv[1].x + p2 * vv[2].x + p3 * vv[3].x;
      acc[g].y = acc[g].y * f + p0 * vv[0].y + p1 * vv[1].y + p2 * vv[2].y + p3 * vv[3].y;
      acc[g].z = acc[g].z * f + p0 * vv[0].z + p1 * vv[1].z + p2 * vv[2].z + p3 * vv[3].z;
      acc[g].w = acc[g].w * f + p0 * vv[0].w + p1 * vv[1].w + p2 * vv[2].w + p3 * vv[3].w;
      mrun[g] = mn;
    }
  }

  // ---------------- emit partials (each half-wave owns its head; no merge) ----------------
  const int sh = s * kNumKVHeads + hh;
  float* accw = ws + ((size_t)sh * kMaxChunks + c) * (kGQA * kHeadDim);
  #pragma unroll
  for (int g = 0; g < kGQA; ++g)
    *(float4*)(accw + g * kHeadDim + 4 * j) = acc[g];
  if (j == 0) {
    float* mw = ws + kMOff + ((size_t)sh * kMaxChunks + c) * kGQA;
    float* lw = ws + kLOff + ((size_t)sh * kMaxChunks + c) * kGQA;
    #pragma unroll
    for (int g = 0; g < kGQA; ++g) { mw[g] = mrun[g]; lw[g] = lrun[g]; }
  }
}

__launch_bounds__(128)
__global__ void paged_attn_reduce(const float* __restrict__ ws,
                                  const int* __restrict__ context_lens,
                                  float* __restrict__ out)
{
  const int idx = blockIdx.x;          // sh*4 + g
  const int g   = idx & 3;
  const int sh  = idx >> 2;
  const int d   = threadIdx.x;
  const int s   = sh >> 3;
  const int h   = sh & 7;

  const int nch = (context_lens[s] + kChunk - 1) / kChunk;   // 16..32 live chunks

  const float* mw = ws + kMOff + (size_t)sh * (kMaxChunks * kGQA);
  const float* lw = ws + kLOff + (size_t)sh * (kMaxChunks * kGQA);

  float mstar = -3.0e38f;
  for (int p = 0; p < nch; ++p) mstar = fmaxf(mstar, mw[p * kGQA + g]);

  float lstar = 0.0f, o = 0.0f;
  for (int p = 0; p < nch; ++p) {
    const float w = __expf(mw[p * kGQA + g] - mstar);
    lstar += w * lw[p * kGQA + g];
    const float* accp =
        ws + ((size_t)sh * kMaxChunks + p) * (kGQA * kHeadDim) + (size_t)g * kHeadDim;
    o += w * accp[d];
  }
  out[(size_t)s * (kNumHeads * kHeadDim) + (h * kGQA + g) * kHeadDim + d] = o / lstar;
}

extern "C" void kernel_launch(void* const* d_in, const int* in_sizes, int n_in,
                              void* d_out, int out_size, void* d_ws, size_t ws_size,
                              hipStream_t stream) {
  const float* q            = (const float*)d_in[0];
  const float* k            = (const float*)d_in[1];
  const float* v            = (const float*)d_in[2];
  const float* k_cache      = (const float*)d_in[3];
  const float* v_cache      = (const float*)d_in[4];
  const float* qw           = (const float*)d_in[5];
  const float* kw           = (const float*)d_in[6];
  const float* cosc         = (const float*)d_in[7];
  const float* sinc         = (const float*)d_in[8];
  const int*   position     = (const int*)d_in[9];
  const int*   block_tables = (const int*)d_in[11];
  const int*   context_lens = (const int*)d_in[12];
  float* out                = (float*)d_out;
  float* ws                 = (float*)d_ws;

  hipLaunchKernelGGL(paged_attn_part, dim3(kMaxChunks * kNumSeqs), dim3(256), 0, stream,
                     q, k, v, k_cache, v_cache, qw, kw, cosc, sinc,
                     position, block_tables, context_lens, ws);
  hipLaunchKernelGGL(paged_attn_reduce, dim3(kNumSH * kGQA), dim3(kHeadDim), 0, stream,
                     ws, context_lens, out);
}

// Round 18
// 91.679 us; speedup vs baseline: 1.2745x; 1.2745x over previous
//
#include <hip/hip_runtime.h>
#include <math.h>

constexpr int kNumSeqs      = 64;
constexpr int kNumHeads     = 32;
constexpr int kNumKVHeads   = 8;
constexpr int kHeadDim      = 128;
constexpr int kGQA          = 4;       // 32/8
constexpr int kKVBlock      = 16;
constexpr int kMaxSeqlen    = 1024;
constexpr int kBlocksPerSeq = 64;
constexpr int kPart         = 4;       // split-K partitions
constexpr int kPartSize     = 256;     // positions per partition
constexpr float kScale      = 0.08838834764831845f;  // 1/sqrt(128)
constexpr float kEps        = 1e-6f;

constexpr size_t kAccElems = (size_t)kNumSeqs * kNumKVHeads * kPart * kGQA * kHeadDim;
constexpr size_t kMOff     = kAccElems;
constexpr size_t kLOff     = kAccElems + (size_t)kNumSeqs * kNumKVHeads * kPart * kGQA;

// Identical to the 94.4us round-9 kernel EXCEPT the blockIdx mapping:
//   OLD: bx = s*32 + h*4 + part  -> 8 heads of one (s,part) at stride 4 -> 8 DIFFERENT XCDs
//        -> each XCD L2 pulls 512B of every 4KB KV row -> HBM sees 8 scattered 512B bursts.
//   NEW: bx = h*256 + s*4 + part -> heads at stride 256 == 0 (mod 8) -> SAME XCD
//        -> the 8 co-resident head-blocks' 512B slices merge in one L2 -> full-row HBM streams.
// All 2048 blocks co-resident (19.5KB LDS -> 8 blk/CU), so heads run in near-lockstep.
__launch_bounds__(256, 4)
__global__ void paged_attn_part(
    const float* __restrict__ q,
    const float* __restrict__ k,
    const float* __restrict__ v,
    const float* __restrict__ k_cache,
    const float* __restrict__ v_cache,
    const float* __restrict__ qw,
    const float* __restrict__ kw,
    const float* __restrict__ cos_cache,
    const float* __restrict__ sin_cache,
    const int*   __restrict__ position,
    const int*   __restrict__ block_tables,
    const int*   __restrict__ context_lens,
    float* __restrict__ ws)
{
  const int bx   = blockIdx.x;
  const int h    = bx >> 8;            // 0..7  (high bits: head)
  const int sp   = bx & 255;
  const int s    = sp >> 2;            // 0..63
  const int part = sp & 3;             // 0..3
  const int tid  = threadIdx.x;
  const int wave = tid >> 6;
  const int lane = tid & 63;

  const int ctx = context_lens[s];
  const int pos = position[s];                 // == ctx-1
  const int n0  = part * kPartSize;

  float* accw = ws + ((((size_t)s * kNumKVHeads + h) * kPart + part) * kGQA) * kHeadDim;
  float* mw   = ws + kMOff + (((size_t)s * kNumKVHeads + h) * kPart + part) * kGQA;
  float* lw   = ws + kLOff + (((size_t)s * kNumKVHeads + h) * kPart + part) * kGQA;

  if (n0 >= ctx) {                              // empty partition: neutral element
    for (int e = tid; e < kGQA * kHeadDim; e += 256) accw[e] = 0.0f;
    if (tid < kGQA) { mw[tid] = -3.0e38f; lw[tid] = 0.0f; }
    return;
  }
  const int cnt      = min(n0 + kPartSize, ctx) - n0;   // 1..256
  const int posLocal = pos - n0;
  const bool haspos  = (posLocal >= 0) && (posLocal < cnt);

  __shared__ __align__(16) float q_lds[kGQA][kHeadDim];
  __shared__ __align__(16) float kn_lds[kHeadDim];
  __shared__ __align__(16) float vn_lds[kHeadDim];
  __shared__ int bt_lds[kPartSize / kKVBlock];             // 16 blocks
  __shared__ __align__(16) float macc[8][kGQA][kHeadDim];  // per half-wave partials (16 KB)
  __shared__ float mm[8][kGQA];
  __shared__ float ml[8][kGQA];

  // ---------------- prologue: RMSNorm + RoPE, stage new k/v + block table ----------------
  {
    const int g = wave;
    const float* qrow = q + (size_t)s * (kNumHeads * kHeadDim) + (h * kGQA + g) * kHeadDim;
    float x1 = qrow[lane];
    float x2 = qrow[lane + 64];
    float ss = x1 * x1 + x2 * x2;
    for (int off = 32; off >= 1; off >>= 1) ss += __shfl_xor(ss, off);
    const float r = rsqrtf(ss * (1.0f / kHeadDim) + kEps);
    x1 *= r * qw[lane];
    x2 *= r * qw[lane + 64];
    const float c  = cos_cache[pos * 64 + lane];
    const float sn = sin_cache[pos * 64 + lane];
    q_lds[g][lane]      = (x1 * c - x2 * sn) * kScale;
    q_lds[g][lane + 64] = (x2 * c + x1 * sn) * kScale;
  }
  if (wave == 0) {
    const float* krow = k + (size_t)s * (kNumKVHeads * kHeadDim) + h * kHeadDim;
    float x1 = krow[lane];
    float x2 = krow[lane + 64];
    float ss = x1 * x1 + x2 * x2;
    for (int off = 32; off >= 1; off >>= 1) ss += __shfl_xor(ss, off);
    const float r = rsqrtf(ss * (1.0f / kHeadDim) + kEps);
    x1 *= r * kw[lane];
    x2 *= r * kw[lane + 64];
    const float c  = cos_cache[pos * 64 + lane];
    const float sn = sin_cache[pos * 64 + lane];
    kn_lds[lane]      = x1 * c - x2 * sn;
    kn_lds[lane + 64] = x2 * c + x1 * sn;
  } else if (wave == 1) {
    const float* vrow = v + (size_t)s * (kNumKVHeads * kHeadDim) + h * kHeadDim;
    vn_lds[lane]      = vrow[lane];
    vn_lds[lane + 64] = vrow[lane + 64];
  } else if (wave == 2) {
    if (lane < kPartSize / kKVBlock)
      bt_lds[lane] = block_tables[s * kBlocksPerSeq + part * (kPartSize / kKVBlock) + lane];
  }
  __syncthreads();   // B1

  const int half = lane >> 5;       // which of the 2 positions in a pair
  const int l    = lane & 31;       // dim chunk: floats [4l, 4l+4)

  float4 qf[kGQA];
  #pragma unroll
  for (int g = 0; g < kGQA; ++g)
    qf[g] = *(const float4*)&q_lds[g][4 * l];

  const int npairs = (cnt + 1) >> 1;   // 1..128

  // ---------------- single-pass flash loop (4 K-loads + 4 V-loads in flight / wave) ------
  float mrun[kGQA], lrun[kGQA];
  float4 acc[kGQA];
  #pragma unroll
  for (int g = 0; g < kGQA; ++g) {
    mrun[g] = -3.0e38f; lrun[g] = 0.0f;
    acc[g] = make_float4(0.f, 0.f, 0.f, 0.f);
  }

  for (int b = 0; wave + 16 * b < npairs; ++b) {
    float4 kv[4], vv[4];
    bool   val[4];
    #pragma unroll
    for (int jj = 0; jj < 4; ++jj) {
      const int  p  = wave + 16 * b + 4 * jj;
      const bool pv = (p < npairs);
      const int  pp = pv ? p : (npairs - 1);
      const int  n  = 2 * pp + half;
      val[jj] = pv && (n < cnt);
      const int  nn = (n < cnt) ? n : (cnt - 1);
      const int  blk = bt_lds[nn >> 4];
      const size_t base = (((size_t)blk * kKVBlock + (nn & 15)) * kNumKVHeads + h) * kHeadDim;
      kv[jj] = *(const float4*)(k_cache + base + 4 * l);
      vv[jj] = *(const float4*)(v_cache + base + 4 * l);
      if (haspos && nn == posLocal) {            // virtual cache insert (new k/v)
        kv[jj] = *(const float4*)&kn_lds[4 * l];
        vv[jj] = *(const float4*)&vn_lds[4 * l];
      }
    }

    float sg[4][kGQA];
    #pragma unroll
    for (int jj = 0; jj < 4; ++jj) {
      #pragma unroll
      for (int g = 0; g < kGQA; ++g)
        sg[jj][g] = qf[g].x * kv[jj].x + qf[g].y * kv[jj].y +
                    qf[g].z * kv[jj].z + qf[g].w * kv[jj].w;
    }
    #pragma unroll
    for (int off = 16; off >= 1; off >>= 1) {
      #pragma unroll
      for (int jj = 0; jj < 4; ++jj) {
        #pragma unroll
        for (int g = 0; g < kGQA; ++g) sg[jj][g] += __shfl_xor(sg[jj][g], off);
      }
    }
    #pragma unroll
    for (int jj = 0; jj < 4; ++jj) {
      if (!val[jj]) {
        #pragma unroll
        for (int g = 0; g < kGQA; ++g) sg[jj][g] = -3.0e38f;
      }
    }

    // online softmax update, independent per half-wave
    #pragma unroll
    for (int g = 0; g < kGQA; ++g) {
      const float mb = fmaxf(fmaxf(sg[0][g], sg[1][g]), fmaxf(sg[2][g], sg[3][g]));
      const float mn = fmaxf(mrun[g], mb);
      const float f  = __expf(mrun[g] - mn);
      const float p0 = __expf(sg[0][g] - mn);
      const float p1 = __expf(sg[1][g] - mn);
      const float p2 = __expf(sg[2][g] - mn);
      const float p3 = __expf(sg[3][g] - mn);
      lrun[g] = lrun[g] * f + (p0 + p1 + p2 + p3);
      acc[g].x = acc[g].x * f + p0 * vv[0].x + p1 * vv[1].x + p2 * vv[2].x + p3 * vv[3].x;
      acc[g].y = acc[g].y * f + p0 * vv[0].y + p1 * vv[1].y + p2 * vv[2].y + p3 * vv[3].y;
      acc[g].z = acc[g].z * f + p0 * vv[0].z + p1 * vv[1].z + p2 * vv[2].z + p3 * vv[3].z;
      acc[g].w = acc[g].w * f + p0 * vv[0].w + p1 * vv[1].w + p2 * vv[2].w + p3 * vv[3].w;
      mrun[g] = mn;
    }
  }

  // ---------------- stash 8 half-wave partials ----------------
  {
    const int idx = wave * 2 + half;
    #pragma unroll
    for (int g = 0; g < kGQA; ++g)
      *(float4*)&macc[idx][g][4 * l] = acc[g];
    if (l == 0) {
      #pragma unroll
      for (int g = 0; g < kGQA; ++g) { mm[idx][g] = mrun[g]; ml[idx][g] = lrun[g]; }
    }
  }
  __syncthreads();   // B2

  // ---------------- merge halves, emit partition partial ----------------
  for (int e = tid; e < kGQA * kHeadDim; e += 256) {
    const int g = e >> 7;
    const int d = e & 127;
    float ms = mm[0][g];
    #pragma unroll
    for (int i = 1; i < 8; ++i) ms = fmaxf(ms, mm[i][g]);
    float ls = 0.0f, o = 0.0f;
    #pragma unroll
    for (int i = 0; i < 8; ++i) {
      const float w = __expf(mm[i][g] - ms);
      ls += w * ml[i][g];
      o  += w * macc[i][g][d];
    }
    accw[e] = o;
    if (d == 0) { mw[g] = ms; lw[g] = ls; }
  }
}

__launch_bounds__(128)
__global__ void paged_attn_reduce(const float* __restrict__ ws,
                                  float* __restrict__ out)
{
  const int idx = blockIdx.x;          // (s*8+h)*4 + g
  const int g   = idx & 3;
  const int sh  = idx >> 2;
  const int d   = threadIdx.x;

  const float* mw = ws + kMOff + (size_t)sh * (kPart * kGQA);
  const float* lw = ws + kLOff + (size_t)sh * (kPart * kGQA);

  float m[kPart];
  #pragma unroll
  for (int p = 0; p < kPart; ++p) m[p] = mw[p * kGQA + g];
  float mstar = m[0];
  #pragma unroll
  for (int p = 1; p < kPart; ++p) mstar = fmaxf(mstar, m[p]);

  float w[kPart], lstar = 0.0f;
  #pragma unroll
  for (int p = 0; p < kPart; ++p) {
    w[p] = __expf(m[p] - mstar);
    lstar += w[p] * lw[p * kGQA + g];
  }

  float o = 0.0f;
  #pragma unroll
  for (int p = 0; p < kPart; ++p) {
    const float* accp = ws + (((size_t)sh * kPart + p) * kGQA + g) * kHeadDim;
    o += w[p] * accp[d];
  }
  const int s = sh >> 3, h = sh & 7;
  out[(size_t)s * (kNumHeads * kHeadDim) + (h * kGQA + g) * kHeadDim + d] = o / lstar;
}

extern "C" void kernel_launch(void* const* d_in, const int* in_sizes, int n_in,
                              void* d_out, int out_size, void* d_ws, size_t ws_size,
                              hipStream_t stream) {
  const float* q            = (const float*)d_in[0];
  const float* k            = (const float*)d_in[1];
  const float* v            = (const float*)d_in[2];
  const float* k_cache      = (const float*)d_in[3];
  const float* v_cache      = (const float*)d_in[4];
  const float* qw           = (const float*)d_in[5];
  const float* kw           = (const float*)d_in[6];
  const float* cosc         = (const float*)d_in[7];
  const float* sinc         = (const float*)d_in[8];
  const int*   position     = (const int*)d_in[9];
  const int*   block_tables = (const int*)d_in[11];
  const int*   context_lens = (const int*)d_in[12];
  float* out                = (float*)d_out;
  float* ws                 = (float*)d_ws;

  hipLaunchKernelGGL(paged_attn_part, dim3(kNumSeqs * kNumKVHeads * kPart), dim3(256),
                     0, stream,
                     q, k, v, k_cache, v_cache, qw, kw, cosc, sinc,
                     position, block_tables, context_lens, ws);
  hipLaunchKernelGGL(paged_attn_reduce, dim3(kNumSeqs * kNumKVHeads * kGQA), dim3(kHeadDim),
                     0, stream, ws, out);
}